// Round 14
// baseline (5874.427 us; speedup 1.0000x reference)
//
#include <hip/hip_runtime.h>
#include <hip/hip_bf16.h>

// Problem constants (B,T,D,L) = (16, 4096, 256, 512)
#define RNN_B 16
#define RNN_T 4096
#define RNN_D 256
#define RNN_L 512

typedef __fp16   fp16x2 __attribute__((ext_vector_type(2)));  // builtin-compatible
typedef _Float16 f16x8  __attribute__((ext_vector_type(8)));  // MFMA fragment
typedef float    f32x4  __attribute__((ext_vector_type(4)));

__device__ __forceinline__ unsigned pk2(float a, float b) {
    auto h = __builtin_amdgcn_cvt_pkrtz(a, b);   // __fp16 ext_vector(2)
    return __builtin_bit_cast(unsigned, h);
}

__device__ __forceinline__ uint4 pk4(float4 a, float4 b) {
    uint4 u;
    u.x = pk2(a.x, a.y); u.y = pk2(a.z, a.w);
    u.z = pk2(b.x, b.y); u.w = pk2(b.z, b.w);
    return u;
}

__device__ __forceinline__ float dot2u(unsigned wa, unsigned hb, float c) {
#if defined(__has_builtin) && __has_builtin(__builtin_amdgcn_fdot2)
    return __builtin_amdgcn_fdot2(__builtin_bit_cast(fp16x2, wa),
                                  __builtin_bit_cast(fp16x2, hb), c, false);
#else
    fp16x2 a = __builtin_bit_cast(fp16x2, wa), b = __builtin_bit_cast(fp16x2, hb);
    return c + (float)a[0] * (float)b[0] + (float)a[1] * (float)b[1];
#endif
}

// ---------------------------------------------------------------------------
// K0: zero the exchange slots (EVERY launch; graph-replay safe: stale seq from
// a previous replay would otherwise satisfy polls). 8192 u64 = 16384 u32.
// ---------------------------------------------------------------------------
__global__ __launch_bounds__(512) void init_slots(unsigned* __restrict__ ws) {
    ws[blockIdx.x * 512 + threadIdx.x] = 0u;     // 32 blocks x 512
}

// ---------------------------------------------------------------------------
// K1: Z[t,b,l] = sum_k x[b,t,k] * Wi[l,k] + bm[l] (f32 into hidden region).
// ---------------------------------------------------------------------------
__global__ __launch_bounds__(256) void proj_kernel(
        const float* __restrict__ x, const float* __restrict__ Wi,
        const float* __restrict__ bm, float* __restrict__ Zout) {
    __shared__ __align__(16) _Float16 As[64 * 40];
    __shared__ __align__(16) _Float16 Bs[64 * 40];

    const int bid = blockIdx.x;
    const int mt = bid >> 3, nt = bid & 7;
    const int mBase = mt * 64, nBase = nt * 64;
    const int tid = threadIdx.x;
    const int w = tid >> 6, l = tid & 63;

    const int srow = tid >> 2, skc = (tid & 3) * 8;
    const int m = mBase + srow;
    const int bb = m & 15, tt = m >> 4;
    const float* ax = x + ((size_t)bb * RNN_T + tt) * RNN_D + skc;
    const float* bw = Wi + (size_t)(nBase + srow) * RNN_D + skc;

    f32x4 acc[4] = {};

#pragma unroll 1
    for (int k0 = 0; k0 < RNN_D; k0 += 32) {
        __syncthreads();
        float4 a0 = *(const float4*)(ax + k0);
        float4 a1 = *(const float4*)(ax + k0 + 4);
        float4 b0 = *(const float4*)(bw + k0);
        float4 b1 = *(const float4*)(bw + k0 + 4);
        uint4 ua = {pk2(a0.x, a0.y), pk2(a0.z, a0.w), pk2(a1.x, a1.y), pk2(a1.z, a1.w)};
        uint4 ub = {pk2(b0.x, b0.y), pk2(b0.z, b0.w), pk2(b1.x, b1.y), pk2(b1.z, b1.w)};
        *(uint4*)(As + srow * 40 + skc) = ua;
        *(uint4*)(Bs + srow * 40 + skc) = ub;
        __syncthreads();

        f16x8 af = *(const f16x8*)(As + (w * 16 + (l & 15)) * 40 + (l >> 4) * 8);
#pragma unroll
        for (int n = 0; n < 4; ++n) {
            f16x8 bf = *(const f16x8*)(Bs + (n * 16 + (l & 15)) * 40 + (l >> 4) * 8);
            acc[n] = __builtin_amdgcn_mfma_f32_16x16x32_f16(af, bf, acc[n], 0, 0, 0);
        }
    }

    const int colL = l & 15, rg = l >> 4;
#pragma unroll
    for (int n = 0; n < 4; ++n) {
        const int col = nBase + n * 16 + colL;
        const float bias = bm[col];
#pragma unroll
        for (int q = 0; q < 4; ++q) {
            const int row = mBase + w * 16 + rg * 4 + q;
            Zout[(size_t)row * RNN_L + col] = acc[n][q] + bias;
        }
    }
}

// ---------------------------------------------------------------------------
// K2: sequential scan, 4 CUs per batch (64 blocks x 512 thr), single-stage
// fused {seq,data} exchange (R13, step 3030 cyc). R13 forensics: the z-
// prefetch was issued BEFORE the poll loop, so every poll iteration's
// s_waitcnt vmcnt(0) (for its own atomic load) also drained the ~900-cyc HBM
// z-load — vmcnt is a single counter. R14: issue the z-prefetch AFTER the
// acquire loop (sched_barrier(0)-pinned); consumption is ~1500 cyc later so
// HBM latency stays hidden, and the poll now waits only on its own L2 load.
// Everything else identical to R13.
// ---------------------------------------------------------------------------
#define DOTG(g, h0_, h1_, h2_, h3_) do { \
    a0 = dot2u(A##g.x, h0_, a0); a0 = dot2u(A##g.y, h1_, a0); \
    a0 = dot2u(A##g.z, h2_, a0); a0 = dot2u(A##g.w, h3_, a0); \
    a1 = dot2u(B##g.x, h0_, a1); a1 = dot2u(B##g.y, h1_, a1); \
    a1 = dot2u(B##g.z, h2_, a1); a1 = dot2u(B##g.w, h3_, a1); } while (0)
#define HRL(i) const unsigned hp##i = (unsigned)__builtin_amdgcn_readlane((int)hv, i)

__global__ __launch_bounds__(512) void rnn_scan4(
        const float* __restrict__ Wm, float* __restrict__ out_h,
        unsigned long long* slots /* [2][16][256] u64: {seq, h-pair} */) {
    __shared__ float part[2][8 * 128];               // 8 KB, double-buffered

    const int bid = blockIdx.x;
    const int b = bid & 15, q = bid >> 4;
    const int tid = threadIdx.x;
    const int w = tid >> 6, l = tid & 63;

    // ---- prologue: 2 channels x 8 uint4 weights -> named VGPRs (64 u32) ----
    const int ch0 = 128 * q + 2 * l;
    const float4* r0 = (const float4*)(Wm + (size_t)ch0 * RNN_L + 64 * w);
    const float4* r1 = (const float4*)(Wm + (size_t)(ch0 + 1) * RNN_L + 64 * w);
    uint4 A0 = pk4(r0[0],  r0[1]),  A1 = pk4(r0[2],  r0[3]);
    uint4 A2 = pk4(r0[4],  r0[5]),  A3 = pk4(r0[6],  r0[7]);
    uint4 A4 = pk4(r0[8],  r0[9]),  A5 = pk4(r0[10], r0[11]);
    uint4 A6 = pk4(r0[12], r0[13]), A7 = pk4(r0[14], r0[15]);
    uint4 B0 = pk4(r1[0],  r1[1]),  B1 = pk4(r1[2],  r1[3]);
    uint4 B2 = pk4(r1[4],  r1[5]),  B3 = pk4(r1[6],  r1[7]);
    uint4 B4 = pk4(r1[8],  r1[9]),  B5 = pk4(r1[10], r1[11]);
    uint4 B6 = pk4(r1[12], r1[13]), B7 = pk4(r1[14], r1[15]);

    // reduce-phase identity: thread handles global channel gch (4-fold dup)
    const int rch = tid >> 2, sub = tid & 3;         // rch 0..127
    const int gch = 128 * q + rch;
    float* zh = out_h + (size_t)b * RNN_L + gch;     // Z in, h out (f32)
    float z = zh[0];

#pragma unroll 1
    for (int t = 0; t < RNN_T; ++t) {
        // ---- acquire h[t]: poll own fused {seq,data} word (l < 32) ----
        unsigned hv = 0;
        if (t > 0) {
            unsigned long long* sp =
                slots + (size_t)(t & 1) * 4096 + b * 256 + 32 * w + l;
            bool rdy = (l >= 32);
            unsigned long long v = 0;
            while (!__all(rdy)) {
                if (!rdy) {
                    v = __hip_atomic_load(sp, __ATOMIC_RELAXED,
                                          __HIP_MEMORY_SCOPE_AGENT);
                    rdy = ((unsigned)(v >> 32) == (unsigned)t);
                }
            }
            hv = (unsigned)v;
        }
        __builtin_amdgcn_sched_barrier(0);   // keep the z-prefetch BELOW the
                                             // poll: its HBM latency must not
                                             // enter the poll's vmcnt drain
        const int tn = (t < RNN_T - 1) ? t + 1 : t;
        const float znext = zh[(size_t)tn * (RNN_B * RNN_L)];   // hidden: used
                                                                // ~1500cy later
        HRL(0);  HRL(1);  HRL(2);  HRL(3);  HRL(4);  HRL(5);  HRL(6);  HRL(7);
        HRL(8);  HRL(9);  HRL(10); HRL(11); HRL(12); HRL(13); HRL(14); HRL(15);
        HRL(16); HRL(17); HRL(18); HRL(19); HRL(20); HRL(21); HRL(22); HRL(23);
        HRL(24); HRL(25); HRL(26); HRL(27); HRL(28); HRL(29); HRL(30); HRL(31);

        // ---- partials over this wave's k-slice ----
        float a0 = 0.f, a1 = 0.f;
        DOTG(0, hp0,  hp1,  hp2,  hp3);   DOTG(1, hp4,  hp5,  hp6,  hp7);
        DOTG(2, hp8,  hp9,  hp10, hp11);  DOTG(3, hp12, hp13, hp14, hp15);
        DOTG(4, hp16, hp17, hp18, hp19);  DOTG(5, hp20, hp21, hp22, hp23);
        DOTG(6, hp24, hp25, hp26, hp27);  DOTG(7, hp28, hp29, hp30, hp31);

        float* pc = part[t & 1];
        *(float2*)&pc[w * 128 + 2 * l] = make_float2(a0, a1);
        __syncthreads();      // B1: partials visible; also the protocol
                              // linchpin (all polls of seq t precede it,
                              // the publish of seq t+1 follows it)

        // ---- reduce channel rch (4 threads/channel) ----
        float s = pc[(2 * sub) * 128 + rch] + pc[(2 * sub + 1) * 128 + rch];
        s += __shfl_xor(s, 1);
        s += __shfl_xor(s, 2);

        const float pre = z + s;
        const float hn = 1.f / (1.f + __expf(-pre));

        // ---- publish h[t+1]: fused {seq=t+1, f16-pair} one-shot store ----
        const float hnb = __shfl_down(hn, 4);        // hn of channel rch+1
        if (sub == 0) {
            if (!(rch & 1)) {
                const unsigned long long pv =
                    (unsigned long long)pk2(hn, hnb) |
                    ((unsigned long long)(unsigned)(t + 1) << 32);
                __hip_atomic_store(
                    &slots[(size_t)((t + 1) & 1) * 4096 + b * 256 + 64 * q + (rch >> 1)],
                    pv, __ATOMIC_RELAXED, __HIP_MEMORY_SCOPE_AGENT);
            }
            zh[(size_t)t * (RNN_B * RNN_L)] = hn;    // fire-and-forget
        }
        z = znext;
    }
}

// ---------------------------------------------------------------------------
// K3: o[t,b] = sum_j Wo[j] * h[t,b,j]. Memory-bound re-read of h (~134 MB).
// Overwrites the out_o region (which held the exchange slots).
// ---------------------------------------------------------------------------
__global__ __launch_bounds__(256) void out_proj(
        const float* __restrict__ Wo, const float* __restrict__ h,
        float* __restrict__ o) {
    const int l = threadIdx.x & 63;
    const int r = blockIdx.x * 4 + (threadIdx.x >> 6);   // r = t*B + b
    const float4* hp = (const float4*)(h + (size_t)r * RNN_L);
    const float4* wp = (const float4*)Wo;
    float4 a0 = hp[l * 2], a1 = hp[l * 2 + 1];
    float4 b0 = wp[l * 2], b1 = wp[l * 2 + 1];
    float s = a0.x * b0.x + a0.y * b0.y + a0.z * b0.z + a0.w * b0.w
            + a1.x * b1.x + a1.y * b1.y + a1.z * b1.z + a1.w * b1.w;
#pragma unroll
    for (int off = 1; off < 64; off <<= 1) s += __shfl_xor(s, off);
    if (l == 0) o[r] = s;
}

// ---------------------------------------------------------------------------
extern "C" void kernel_launch(void* const* d_in, const int* in_sizes, int n_in,
                              void* d_out, int out_size, void* d_ws, size_t ws_size,
                              hipStream_t stream) {
    const float* x  = (const float*)d_in[0];   // [16,4096,256]
    const float* Wi = (const float*)d_in[1];   // [512,256]
    const float* Wm = (const float*)d_in[2];   // [512,512]
    const float* bm = (const float*)d_in[3];   // [512]
    const float* Wo = (const float*)d_in[4];   // [1,512]

    float* out_o = (float*)d_out;                 // [T*B] floats (256 KB)
    float* out_h = out_o + (RNN_T * RNN_B);       // [T*B*L] floats
    unsigned long long* slots = (unsigned long long*)out_o;   // 64 KB scratch

    // K0: zero the fused exchange slots (every launch; graph-replay safe)
    init_slots<<<dim3(32), dim3(512), 0, stream>>>((unsigned*)slots);

    // K1: Z = x @ Wi^T + bm  -> hidden region (scratch, overwritten by K2)
    proj_kernel<<<dim3((RNN_T * RNN_B / 64) * (RNN_L / 64)), dim3(256), 0, stream>>>(
        x, Wi, bm, out_h);

    // K2: sequential recurrence, 4 blocks/batch, single-stage fused exchange
    rnn_scan4<<<dim3(64), dim3(512), 0, stream>>>(Wm, out_h, slots);

    // K3: o = h . Wo (overwrites the scratch region with real outputs)
    out_proj<<<dim3(RNN_T * RNN_B / 4), dim3(256), 0, stream>>>(Wo, out_h, out_o);
}